// Round 6
// baseline (2207.080 us; speedup 1.0000x reference)
//
#include <hip/hip_runtime.h>
#include <stdint.h>

typedef __attribute__((ext_vector_type(8))) short bf16x8;
typedef __attribute__((ext_vector_type(4))) float f32x4;

#define N_NODES 8192
#define E_EDGES 163840
#define NGRAPH  32
#define MT      128         /* edges per block */

#define INV_SQRT30 0.18257419f
#define SH0C       0.22360680f   /* 1/sqrt(20) */
#define SQRT3C     1.73205081f
#define INV_SQRT3  0.57735027f
#define INV_SQRT10 0.31622777f
#define SQ2C       0.70710678f

// ---------------- workspace layout (bytes) ----------------
enum : unsigned {
  OFF_W1P1 = 0u,       OFF_W2P1 = 65536u,   OFF_W3P1 = 589824u,  OFF_W4P1 = 655360u,
  OFF_W1P2 = 851968u,  OFF_W2P2 = 917504u,  OFF_W3P2 = 1441792u, OFF_W4P2 = 1507328u,
  OFF_B1P1 = 1515520u, OFF_B2P1 = 1517568u, OFF_B3P1 = 1519616u, OFF_B4P1 = 1519872u,
  OFF_B1P2 = 1526016u, OFF_B2P2 = 1528064u, OFF_B3P2 = 1530112u, OFF_B4P2 = 1530368u,
  OFF_HN   = 1530624u, // [8192][32] f32  (emb[z]/sqrt(30))
  OFF_H2   = 2579200u, // [8192][64] f32
  OFF_AGG  = 4676352u, // [8192][70] f32
  OFF_AGG2 = 6970112u, // [8192] f32
  OFF_GSUM = 7002880u, // [32] f32
  OFF_END  = 7003008u
};

__device__ __forceinline__ uint16_t f2bf(float f){
  union { float f; uint32_t u; } v; v.f = f;
  uint32_t r = v.u + 0x7fffu + ((v.u >> 16) & 1u);
  return (uint16_t)(r >> 16);
}
__device__ __forceinline__ float swishf(float x){ return x / (1.f + __expf(-x)); }

// ---------------- weight pre-pack (f32 src -> bf16 MFMA B-fragment order) ----------------
__device__ __forceinline__ void pack_mat(const float* __restrict__ src, int K, int N, int NP,
                                         uint16_t* __restrict__ dst, int t)
{
  int lane = t & 63;
  int tile = t >> 6;
  int NT = NP >> 4;
  int nn = tile % NT, kk = tile / NT;
  int k0 = kk*32 + ((lane >> 4) << 3);
  int n  = nn*16 + (lane & 15);
  union { short s[8]; bf16x8 v; } tmp;
#pragma unroll
  for (int b = 0; b < 8; ++b) {
    int k = k0 + b;
    tmp.s[b] = (k < K && n < N) ? (short)f2bf(src[(size_t)k*N + n]) : (short)0;
  }
  *reinterpret_cast<bf16x8*>(dst + (size_t)t*8) = tmp.v;
}

__global__ void prep_kernel(const float* w1a, const float* w2a, const float* w3a, const float* w4a,
                            const float* w1b, const float* w2b, const float* w3b, const float* w4b,
                            const float* b1a, const float* b2a, const float* b3a, const float* b4a,
                            const float* b1b, const float* b2b, const float* b3b, const float* b4b,
                            const float* emb, const int* z, char* ws)
{
  int t = blockIdx.x * 256 + threadIdx.x;
  if      (t < 4096)   pack_mat(w1a, 40, 500, 512,  (uint16_t*)(ws + OFF_W1P1), t);
  else if (t < 36864)  pack_mat(w2a, 500,500, 512,  (uint16_t*)(ws + OFF_W2P1), t - 4096);
  else if (t < 40960)  pack_mat(w3a, 500, 50, 64,   (uint16_t*)(ws + OFF_W3P1), t - 36864);
  else if (t < 53248)  pack_mat(w4a, 50,1500, 1536, (uint16_t*)(ws + OFF_W4P1), t - 40960);
  else if (t < 57344)  pack_mat(w1b, 40, 500, 512,  (uint16_t*)(ws + OFF_W1P2), t - 53248);
  else if (t < 90112)  pack_mat(w2b, 500,500, 512,  (uint16_t*)(ws + OFF_W2P2), t - 57344);
  else if (t < 94208)  pack_mat(w3b, 500, 50, 64,   (uint16_t*)(ws + OFF_W3P2), t - 90112);
  else if (t < 94720)  pack_mat(w4b, 50,  40, 64,   (uint16_t*)(ws + OFF_W4P2), t - 94208);
  else if (t < 98496) {
    int loc = t - 94720;
    const float* src; float* dst; int realN;
    if      (loc < 512)  { src=b1a; dst=(float*)(ws+OFF_B1P1); realN=500; }
    else if (loc < 1024) { src=b2a; dst=(float*)(ws+OFF_B2P1); realN=500;  loc -= 512;  }
    else if (loc < 1088) { src=b3a; dst=(float*)(ws+OFF_B3P1); realN=50;   loc -= 1024; }
    else if (loc < 2624) { src=b4a; dst=(float*)(ws+OFF_B4P1); realN=1500; loc -= 1088; }
    else if (loc < 3136) { src=b1b; dst=(float*)(ws+OFF_B1P2); realN=500;  loc -= 2624; }
    else if (loc < 3648) { src=b2b; dst=(float*)(ws+OFF_B2P2); realN=500;  loc -= 3136; }
    else if (loc < 3712) { src=b3b; dst=(float*)(ws+OFF_B3P2); realN=50;   loc -= 3648; }
    else                 { src=b4b; dst=(float*)(ws+OFF_B4P2); realN=40;   loc -= 3712; }
    dst[loc] = (loc < realN) ? src[loc] : 0.f;
  }
  else if (t < 360640) {
    int i = t - 98496;
    int n = i >> 5, u = i & 31;
    float v = 0.f;
    if (u < 30) v = emb[(size_t)z[n]*30 + u] * INV_SQRT30;
    ((float*)(ws + OFF_HN))[i] = v;
  }
}

// ---------------- GEMM core: acc[RB][NTW] over rows rowbase + rb*16, cols (ntbase+nt)*16 ----------------
template<int KP, int RB, int NTW>
__device__ __forceinline__ void gemm_core(const uint16_t* inb, const uint16_t* __restrict__ Bp,
                                          int NTtot, int ntbase, int rowbase, int lane,
                                          f32x4 (&acc)[RB][NTW])
{
  const int r = lane & 15, q = lane >> 4;
  constexpr int NK = KP/32;
  const bf16x8* __restrict__ bv = reinterpret_cast<const bf16x8*>(Bp);
  const char* inbc = (const char*)inb;
  f32x4 zv = {0.f, 0.f, 0.f, 0.f};
#pragma unroll
  for (int a = 0; a < RB; ++a)
#pragma unroll
    for (int b = 0; b < NTW; ++b) acc[a][b] = zv;

#pragma unroll
  for (int kk = 0; kk < NK; ++kk) {
    bf16x8 afrag[RB];
#pragma unroll
    for (int rb = 0; rb < RB; ++rb) {
      int row = rowbase + rb*16 + r;
      int byte = (row*KP + kk*32 + q*8) * 2; byte ^= ((row & 7) << 4);
      afrag[rb] = *reinterpret_cast<const bf16x8*>(inbc + byte);
    }
    bf16x8 bfrag[NTW];
#pragma unroll
    for (int nt = 0; nt < NTW; ++nt)
      bfrag[nt] = bv[(size_t)(kk*NTtot + ntbase + nt)*64 + lane];
#pragma unroll
    for (int nt = 0; nt < NTW; ++nt)
#pragma unroll
      for (int rb = 0; rb < RB; ++rb)
        acc[rb][nt] = __builtin_amdgcn_mfma_f32_16x16x32_bf16(afrag[rb], bfrag[nt], acc[rb][nt], 0, 0, 0);
  }
}

template<int RB, int NTW>
__device__ __forceinline__ void gemm_epi(uint16_t* outb, const float* __restrict__ bp,
                                         int ntbase, int rowbase, int lane, int outPitchB,
                                         f32x4 (&acc)[RB][NTW])
{
  const int r = lane & 15, q = lane >> 4;
#pragma unroll
  for (int nt = 0; nt < NTW; ++nt) {
    int col = (ntbase + nt)*16 + r;
    float bias = bp[col];
#pragma unroll
    for (int rb = 0; rb < RB; ++rb)
#pragma unroll
      for (int i = 0; i < 4; ++i) {
        int row = rowbase + rb*16 + q*4 + i;
        float v = swishf(acc[rb][nt][i] + bias);
        int byte = row*outPitchB + col*2; byte ^= ((row & 7) << 4);
        *(uint16_t*)((char*)outb + byte) = f2bf(v);
      }
  }
}

// ---------------- edge megakernel (128 edges / block, 8 waves, 1 block/CU) ----------------
template<int LAYER>
__global__ __launch_bounds__(512, 2)
void edge_kernel(const float* __restrict__ pos, const int* __restrict__ eidx,
                 const char* __restrict__ ws, float* __restrict__ aggout,
                 const float* __restrict__ hsrc)
{
  __shared__ __align__(16) uint16_t bigb[MT*512];  // act1 -> act2 -> (overlay: mbuf/xj scratch)
  __shared__ __align__(16) uint16_t smlb[MT*64];   // basis -> x3
  __shared__ float shl[MT*3];
  __shared__ float rbuf[MT];
  __shared__ int   rowl[MT];
  __shared__ int   coll[MT];

  const uint16_t* W1p = (const uint16_t*)(ws + (LAYER==1 ? OFF_W1P1 : OFF_W1P2));
  const uint16_t* W2p = (const uint16_t*)(ws + (LAYER==1 ? OFF_W2P1 : OFF_W2P2));
  const uint16_t* W3p = (const uint16_t*)(ws + (LAYER==1 ? OFF_W3P1 : OFF_W3P2));
  const uint16_t* W4p = (const uint16_t*)(ws + (LAYER==1 ? OFF_W4P1 : OFF_W4P2));
  const float* b1p = (const float*)(ws + (LAYER==1 ? OFF_B1P1 : OFF_B1P2));
  const float* b2p = (const float*)(ws + (LAYER==1 ? OFF_B2P1 : OFF_B2P2));
  const float* b3p = (const float*)(ws + (LAYER==1 ? OFF_B3P1 : OFF_B3P2));
  const float* b4p = (const float*)(ws + (LAYER==1 ? OFF_B4P1 : OFF_B4P2));

  const int tid  = threadIdx.x;
  const int lane = tid & 63;
  const int wv   = tid >> 6;
  const int e0   = blockIdx.x * MT;

  // stage 0: edge meta
  if (tid < MT) {
    int e = e0 + tid;
    int rn = eidx[e];
    int cn = eidx[E_EDGES + e];
    rowl[tid] = rn; coll[tid] = cn;
    float ax = pos[rn*3+0] - pos[cn*3+0];
    float ay = pos[rn*3+1] - pos[cn*3+1];
    float az = pos[rn*3+2] - pos[cn*3+2];
    float rr = sqrtf(ax*ax + ay*ay + az*az + 1e-12f);
    rbuf[tid] = rr;
    float s = SQRT3C * SH0C / rr;
    shl[tid*3+0] = ax*s; shl[tid*3+1] = ay*s; shl[tid*3+2] = az*s;
  }
  __syncthreads();

  // stage 0b: basis into smlb (pitch 64 elems, swizzled bf16)
  for (int i = tid; i < MT*64; i += 512) {
    int e = i >> 6, c = i & 63;
    float v = 0.f;
    if (c < 40) { float t = rbuf[e]*3.9f - (float)c; v = __expf(-t*t); }
    int byte = (e*64 + c)*2; byte ^= ((e & 7) << 4);
    *(uint16_t*)((char*)smlb + byte) = f2bf(v);
  }
  __syncthreads();

  // GEMM1: basis(smlb,64) -> act1(bigb,512), swish.  wave: 8 rowblocks x 4 ntiles
  {
    f32x4 acc[8][4];
    gemm_core<64, 8, 4>(smlb, W1p, 32, wv*4, 0, lane, acc);
    gemm_epi<8, 4>(bigb, b1p, wv*4, 0, lane, 1024, acc);
  }
  __syncthreads();

  // GEMM2: act1(bigb) -> act2(bigb), swish. acc in regs across the barrier (in-place swap)
  {
    f32x4 acc[8][4];
    gemm_core<512, 8, 4>(bigb, W2p, 32, wv*4, 0, lane, acc);
    __syncthreads();   // all waves done READING act1
    gemm_epi<8, 4>(bigb, b2p, wv*4, 0, lane, 1024, acc);
  }
  __syncthreads();

  // GEMM3: act2(bigb) -> x3(smlb,64), swish. wave wv owns rowblock wv, all 4 ntiles
  {
    f32x4 acc[1][4];
    gemm_core<512, 1, 4>(bigb, W3p, 4, 0, wv*16, lane, acc);
    gemm_epi<1, 4>(smlb, b3p, 0, wv*16, lane, 128, acc);
  }
  __syncthreads();

  // stage 6: overlay scratch in bigb (act2 dead), gather xj
  float* const bigf = (float*)bigb;
  if (LAYER == 1) {
    float* mbuf = bigf;               // [MT*50]
    float* xjb  = bigf + MT*50;       // [MT*30]
    for (int i = tid; i < MT*50; i += 512) mbuf[i] = 0.f;
    for (int i = tid; i < MT*30; i += 512) {
      int e = i/30, u = i - e*30;
      xjb[i] = hsrc[(size_t)rowl[e]*32 + u];
    }
  } else {
    float* medge = bigf;              // [MT]
    float* Db    = bigf + MT;         // [MT*10]
    float* xjs   = Db + MT*10;        // [MT*30]
    float* xjv   = xjs + MT*30;       // [MT*30]
    if (tid < MT) medge[tid] = 0.f;
    for (int i = tid; i < MT*60; i += 512) {
      int e = i/60, u = i - e*60;
      float v = hsrc[(size_t)rowl[e]*64 + u];
      if (u < 30) xjs[e*30 + u] = v; else xjv[e*30 + (u - 30)] = v;
    }
    __syncthreads();
    for (int i = tid; i < MT*10; i += 512) {
      int e = i/10, v = i - e*10;
      float d = 0.f;
#pragma unroll
      for (int m = 0; m < 3; ++m) d += xjv[e*30 + v*3 + m] * shl[e*3 + m];
      Db[i] = d * INV_SQRT3;
    }
  }
  __syncthreads();

  // GEMM4 + consumption
  const int r_ = lane & 15, q_ = lane >> 4;
  f32x4 zv = {0.f, 0.f, 0.f, 0.f};
  if (LAYER == 1) {
    float* mbuf = bigf;
    float* xjb  = bigf + MT*50;
    const bf16x8* __restrict__ bv4 = reinterpret_cast<const bf16x8*>(W4p);
#pragma unroll
    for (int rh = 0; rh < 2; ++rh) {          // rowblock halves: rb = rh*4 + rbi
      bf16x8 a4[2][4];
#pragma unroll
      for (int kk = 0; kk < 2; ++kk)
#pragma unroll
        for (int rbi = 0; rbi < 4; ++rbi) {
          int row = (rh*4 + rbi)*16 + r_;
          int byte = (row*64 + kk*32 + q_*8)*2; byte ^= ((row & 7) << 4);
          a4[kk][rbi] = *reinterpret_cast<const bf16x8*>((const char*)smlb + byte);
        }
#pragma unroll
      for (int ch = 0; ch < 3; ++ch) {
        bf16x8 b4[2][4];
#pragma unroll
        for (int kk = 0; kk < 2; ++kk)
#pragma unroll
          for (int nt = 0; nt < 4; ++nt)
            b4[kk][nt] = bv4[(size_t)(kk*96 + wv*12 + ch*4 + nt)*64 + lane];
        f32x4 acc[4][4];
#pragma unroll
        for (int a = 0; a < 4; ++a)
#pragma unroll
          for (int b = 0; b < 4; ++b) acc[a][b] = zv;
#pragma unroll
        for (int kk = 0; kk < 2; ++kk)
#pragma unroll
          for (int nt = 0; nt < 4; ++nt)
#pragma unroll
            for (int rbi = 0; rbi < 4; ++rbi)
              acc[rbi][nt] = __builtin_amdgcn_mfma_f32_16x16x32_bf16(a4[kk][rbi], b4[kk][nt], acc[rbi][nt], 0, 0, 0);
#pragma unroll
        for (int nt = 0; nt < 4; ++nt) {
          int cg = (wv*12 + ch*4 + nt)*16 + r_;
          if (cg < 1500) {
            float bias = b4p[cg];
            int u, vd;
            if (cg < 1200) { u = cg/40; vd = cg - u*40; }
            else { int cc = cg - 1200; u = cc/10; vd = 40 + (cc - u*10); }
#pragma unroll
            for (int rbi = 0; rbi < 4; ++rbi)
#pragma unroll
              for (int i2 = 0; i2 < 4; ++i2) {
                int e = (rh*4 + rbi)*16 + q_*4 + i2;
                float w = acc[rbi][nt][i2] + bias;
                atomicAdd(&mbuf[e*50 + vd], xjb[e*30 + u] * w);
              }
          }
        }
      }
    }
  } else {
    float* medge = bigf;
    float* Db    = bigf + MT;
    float* xjs   = Db + MT*10;
    const bf16x8* __restrict__ bv4 = reinterpret_cast<const bf16x8*>(W4p);
    // wave wv owns rowblock wv; all 4 ntiles (cols 0..63, 40 real)
    bf16x8 a4[2];
#pragma unroll
    for (int kk = 0; kk < 2; ++kk) {
      int row = wv*16 + r_;
      int byte = (row*64 + kk*32 + q_*8)*2; byte ^= ((row & 7) << 4);
      a4[kk] = *reinterpret_cast<const bf16x8*>((const char*)smlb + byte);
    }
    f32x4 acc[4];
#pragma unroll
    for (int a = 0; a < 4; ++a) acc[a] = zv;
#pragma unroll
    for (int kk = 0; kk < 2; ++kk)
#pragma unroll
      for (int nt = 0; nt < 4; ++nt) {
        bf16x8 b4 = bv4[(size_t)(kk*4 + nt)*64 + lane];
        acc[nt] = __builtin_amdgcn_mfma_f32_16x16x32_bf16(a4[kk], b4, acc[nt], 0, 0, 0);
      }
#pragma unroll
    for (int nt = 0; nt < 4; ++nt) {
      int cg = nt*16 + r_;
      if (cg < 40) {
        float bias = b4p[cg];
#pragma unroll
        for (int i2 = 0; i2 < 4; ++i2) {
          int e = wv*16 + q_*4 + i2;
          float w = acc[nt][i2] + bias;
          float contrib = (cg < 30) ? xjs[e*30 + cg] * w * (SH0C * INV_SQRT30)
                                    : Db[e*10 + (cg - 30)] * w * INV_SQRT10;
          atomicAdd(&medge[e], contrib);
        }
      }
    }
  }
  __syncthreads();

  // scatter to aggregation buffers
  if (LAYER == 1) {
    float* mbuf = bigf;
    for (int i = tid; i < MT*70; i += 512) {
      int e = i/70, c = i - e*70;
      float v;
      if (c < 40) v = mbuf[e*50 + c] * SH0C;
      else { int vv = (c - 40)/3, k = (c - 40) - vv*3; v = mbuf[e*50 + 40 + vv] * shl[e*3 + k]; }
      atomicAdd(&aggout[(size_t)coll[e]*70 + c], v);
    }
  } else {
    float* medge = bigf;
    if (tid < MT) atomicAdd(&aggout[coll[tid]], medge[tid]);
  }
}

// ---------------- node kernels ----------------
__global__ void node_mid(char* ws, const float* __restrict__ si1w)
{
  int nid = blockIdx.x * blockDim.x + threadIdx.x;
  if (nid >= N_NODES) return;
  const float* hN  = (const float*)(ws + OFF_HN)  + (size_t)nid*32;
  const float* agg = (const float*)(ws + OFF_AGG) + (size_t)nid*70;
  float* h2        = (float*)(ws + OFF_H2)        + (size_t)nid*64;

  float hn[30];
#pragma unroll
  for (int u = 0; u < 30; ++u) hn[u] = hN[u];

  float h1[70];
#pragma unroll
  for (int v = 0; v < 40; ++v) {
    float s = 0.f;
#pragma unroll
    for (int u = 0; u < 30; ++u) s += hn[u] * si1w[u*40 + v];
    h1[v] = SQ2C * (s + agg[v]);
  }
#pragma unroll
  for (int c = 40; c < 70; ++c) h1[c] = agg[c];

#pragma unroll
  for (int u = 0; u < 30; ++u) h2[u] = swishf(h1[u]);
#pragma unroll
  for (int v = 0; v < 10; ++v) {
    float g = 1.f / (1.f + __expf(-h1[30 + v]));
#pragma unroll
    for (int k = 0; k < 3; ++k) h2[30 + v*3 + k] = h1[40 + v*3 + k] * g;
  }
}

__global__ void node_final(char* ws, const float* __restrict__ si2w, const int* __restrict__ batch)
{
  __shared__ float ls[NGRAPH];
  if (threadIdx.x < NGRAPH) ls[threadIdx.x] = 0.f;
  __syncthreads();
  int nid = blockIdx.x * blockDim.x + threadIdx.x;
  if (nid < N_NODES) {
    const float* h2   = (const float*)(ws + OFF_H2) + (size_t)nid*64;
    const float* agg2 = (const float*)(ws + OFF_AGG2);
    float s2 = 0.f;
#pragma unroll
    for (int u = 0; u < 30; ++u) s2 += h2[u] * si2w[u];
    float val = SQ2C * (s2 * INV_SQRT30 + agg2[nid]);
    atomicAdd(&ls[batch[nid]], val);
  }
  __syncthreads();
  if (threadIdx.x < NGRAPH)
    atomicAdd(((float*)(ws + OFF_GSUM)) + threadIdx.x, ls[threadIdx.x]);
}

__global__ void write_out(const char* ws, float* out)
{
  int g = threadIdx.x;
  if (g < NGRAPH) out[g] = ((const float*)(ws + OFF_GSUM))[g];
}

// ---------------- launch ----------------
extern "C" void kernel_launch(void* const* d_in, const int* in_sizes, int n_in,
                              void* d_out, int out_size, void* d_ws, size_t ws_size,
                              hipStream_t stream)
{
  const float* pos  = (const float*)d_in[0];
  const float* emb  = (const float*)d_in[1];
  const float* si1w = (const float*)d_in[2];
  const float* si2w = (const float*)d_in[3];
  const float* w1a = (const float*)d_in[4];  const float* b1a = (const float*)d_in[5];
  const float* w2a = (const float*)d_in[6];  const float* b2a = (const float*)d_in[7];
  const float* w3a = (const float*)d_in[8];  const float* b3a = (const float*)d_in[9];
  const float* w4a = (const float*)d_in[10]; const float* b4a = (const float*)d_in[11];
  const float* w1b = (const float*)d_in[12]; const float* b1b = (const float*)d_in[13];
  const float* w2b = (const float*)d_in[14]; const float* b2b = (const float*)d_in[15];
  const float* w3b = (const float*)d_in[16]; const float* b3b = (const float*)d_in[17];
  const float* w4b = (const float*)d_in[18]; const float* b4b = (const float*)d_in[19];
  const int* z     = (const int*)d_in[20];
  const int* eidx  = (const int*)d_in[21];
  const int* batch = (const int*)d_in[22];
  char* ws = (char*)d_ws;

  hipMemsetAsync(ws + OFF_AGG, 0, OFF_END - OFF_AGG, stream);

  prep_kernel<<<1409, 256, 0, stream>>>(w1a, w2a, w3a, w4a, w1b, w2b, w3b, w4b,
                                        b1a, b2a, b3a, b4a, b1b, b2b, b3b, b4b,
                                        emb, z, ws);

  edge_kernel<1><<<E_EDGES/MT, 512, 0, stream>>>(pos, eidx, ws,
                                                 (float*)(ws + OFF_AGG),
                                                 (const float*)(ws + OFF_HN));

  node_mid<<<N_NODES/256, 256, 0, stream>>>(ws, si1w);

  edge_kernel<2><<<E_EDGES/MT, 512, 0, stream>>>(pos, eidx, ws,
                                                 (float*)(ws + OFF_AGG2),
                                                 (const float*)(ws + OFF_H2));

  node_final<<<N_NODES/256, 256, 0, stream>>>(ws, si2w, batch);

  write_out<<<1, 64, 0, stream>>>(ws, (float*)d_out);
}

// Round 7
// 1890.700 us; speedup vs baseline: 1.1673x; 1.1673x over previous
//
#include <hip/hip_runtime.h>
#include <stdint.h>

typedef __attribute__((ext_vector_type(8))) short bf16x8;
typedef __attribute__((ext_vector_type(4))) float f32x4;

#define N_NODES 8192
#define E_EDGES 163840
#define NGRAPH  32
#define MT      64          /* edges per block */

#define INV_SQRT30 0.18257419f
#define SH0C       0.22360680f   /* 1/sqrt(20) */
#define SQRT3C     1.73205081f
#define INV_SQRT3  0.57735027f
#define INV_SQRT10 0.31622777f
#define SQ2C       0.70710678f

// ---------------- workspace layout (bytes) ----------------
enum : unsigned {
  OFF_W1P1 = 0u,       OFF_W2P1 = 65536u,   OFF_W3P1 = 589824u,  OFF_W4P1 = 655360u,
  OFF_W1P2 = 851968u,  OFF_W2P2 = 917504u,  OFF_W3P2 = 1441792u, OFF_W4P2 = 1507328u,
  OFF_B1P1 = 1515520u, OFF_B2P1 = 1517568u, OFF_B3P1 = 1519616u, OFF_B4P1 = 1519872u,
  OFF_B1P2 = 1526016u, OFF_B2P2 = 1528064u, OFF_B3P2 = 1530112u, OFF_B4P2 = 1530368u,
  OFF_HN   = 1530624u, // [8192][32] f32  (emb[z]/sqrt(30))
  OFF_H2   = 2579200u, // [8192][64] f32
  OFF_AGG  = 4676352u, // [8192][70] f32
  OFF_AGG2 = 6970112u, // [8192] f32
  OFF_GSUM = 7002880u, // [32] f32
  OFF_END  = 7003008u
};

__device__ __forceinline__ uint16_t f2bf(float f){
  union { float f; uint32_t u; } v; v.f = f;
  uint32_t r = v.u + 0x7fffu + ((v.u >> 16) & 1u);
  return (uint16_t)(r >> 16);
}
__device__ __forceinline__ float swishf(float x){ return x / (1.f + __expf(-x)); }

// ---------------- weight pre-pack (f32 src -> bf16 MFMA B-fragment order) ----------------
__device__ __forceinline__ void pack_mat(const float* __restrict__ src, int K, int N, int NP,
                                         uint16_t* __restrict__ dst, int t)
{
  int lane = t & 63;
  int tile = t >> 6;
  int NT = NP >> 4;
  int nn = tile % NT, kk = tile / NT;
  int k0 = kk*32 + ((lane >> 4) << 3);
  int n  = nn*16 + (lane & 15);
  union { short s[8]; bf16x8 v; } tmp;
#pragma unroll
  for (int b = 0; b < 8; ++b) {
    int k = k0 + b;
    tmp.s[b] = (k < K && n < N) ? (short)f2bf(src[(size_t)k*N + n]) : (short)0;
  }
  *reinterpret_cast<bf16x8*>(dst + (size_t)t*8) = tmp.v;
}

__global__ void prep_kernel(const float* w1a, const float* w2a, const float* w3a, const float* w4a,
                            const float* w1b, const float* w2b, const float* w3b, const float* w4b,
                            const float* b1a, const float* b2a, const float* b3a, const float* b4a,
                            const float* b1b, const float* b2b, const float* b3b, const float* b4b,
                            const float* emb, const int* z, char* ws)
{
  int t = blockIdx.x * 256 + threadIdx.x;
  if      (t < 4096)   pack_mat(w1a, 40, 500, 512,  (uint16_t*)(ws + OFF_W1P1), t);
  else if (t < 36864)  pack_mat(w2a, 500,500, 512,  (uint16_t*)(ws + OFF_W2P1), t - 4096);
  else if (t < 40960)  pack_mat(w3a, 500, 50, 64,   (uint16_t*)(ws + OFF_W3P1), t - 36864);
  else if (t < 53248)  pack_mat(w4a, 50,1500, 1536, (uint16_t*)(ws + OFF_W4P1), t - 40960);
  else if (t < 57344)  pack_mat(w1b, 40, 500, 512,  (uint16_t*)(ws + OFF_W1P2), t - 53248);
  else if (t < 90112)  pack_mat(w2b, 500,500, 512,  (uint16_t*)(ws + OFF_W2P2), t - 57344);
  else if (t < 94208)  pack_mat(w3b, 500, 50, 64,   (uint16_t*)(ws + OFF_W3P2), t - 90112);
  else if (t < 94720)  pack_mat(w4b, 50,  40, 64,   (uint16_t*)(ws + OFF_W4P2), t - 94208);
  else if (t < 98496) {
    int loc = t - 94720;
    const float* src; float* dst; int realN;
    if      (loc < 512)  { src=b1a; dst=(float*)(ws+OFF_B1P1); realN=500; }
    else if (loc < 1024) { src=b2a; dst=(float*)(ws+OFF_B2P1); realN=500;  loc -= 512;  }
    else if (loc < 1088) { src=b3a; dst=(float*)(ws+OFF_B3P1); realN=50;   loc -= 1024; }
    else if (loc < 2624) { src=b4a; dst=(float*)(ws+OFF_B4P1); realN=1500; loc -= 1088; }
    else if (loc < 3136) { src=b1b; dst=(float*)(ws+OFF_B1P2); realN=500;  loc -= 2624; }
    else if (loc < 3648) { src=b2b; dst=(float*)(ws+OFF_B2P2); realN=500;  loc -= 3136; }
    else if (loc < 3712) { src=b3b; dst=(float*)(ws+OFF_B3P2); realN=50;   loc -= 3648; }
    else                 { src=b4b; dst=(float*)(ws+OFF_B4P2); realN=40;   loc -= 3712; }
    dst[loc] = (loc < realN) ? src[loc] : 0.f;
  }
  else if (t < 360640) {
    int i = t - 98496;
    int n = i >> 5, u = i & 31;
    float v = 0.f;
    if (u < 30) v = emb[(size_t)z[n]*30 + u] * INV_SQRT30;
    ((float*)(ws + OFF_HN))[i] = v;
  }
}

// ---------------- GEMM core: acc[RB][NTW], rows rowbase + rb*16, cols (ntbase+nt)*16 ----------------
template<int KP, int RB, int NTW>
__device__ __forceinline__ void gemm_core(const uint16_t* inb, const uint16_t* __restrict__ Bp,
                                          int NTtot, int ntbase, int rowbase, int lane,
                                          f32x4 (&acc)[RB][NTW])
{
  const int r = lane & 15, q = lane >> 4;
  constexpr int NK = KP/32;
  const bf16x8* __restrict__ bv = reinterpret_cast<const bf16x8*>(Bp);
  const char* inbc = (const char*)inb;
  f32x4 zv = {0.f, 0.f, 0.f, 0.f};
#pragma unroll
  for (int a = 0; a < RB; ++a)
#pragma unroll
    for (int b = 0; b < NTW; ++b) acc[a][b] = zv;

#pragma unroll
  for (int kk = 0; kk < NK; ++kk) {
    bf16x8 afrag[RB];
#pragma unroll
    for (int rb = 0; rb < RB; ++rb) {
      int row = rowbase + rb*16 + r;
      int byte = (row*KP + kk*32 + q*8) * 2; byte ^= ((row & 7) << 4);
      afrag[rb] = *reinterpret_cast<const bf16x8*>(inbc + byte);
    }
    bf16x8 bfrag[NTW];
#pragma unroll
    for (int nt = 0; nt < NTW; ++nt)
      bfrag[nt] = bv[(size_t)(kk*NTtot + ntbase + nt)*64 + lane];
#pragma unroll
    for (int nt = 0; nt < NTW; ++nt)
#pragma unroll
      for (int rb = 0; rb < RB; ++rb)
        acc[rb][nt] = __builtin_amdgcn_mfma_f32_16x16x32_bf16(afrag[rb], bfrag[nt], acc[rb][nt], 0, 0, 0);
  }
}

template<int RB, int NTW>
__device__ __forceinline__ void gemm_epi(uint16_t* outb, const float* __restrict__ bp,
                                         int ntbase, int rowbase, int lane, int outPitchB,
                                         f32x4 (&acc)[RB][NTW])
{
  const int r = lane & 15, q = lane >> 4;
#pragma unroll
  for (int nt = 0; nt < NTW; ++nt) {
    int col = (ntbase + nt)*16 + r;
    float bias = bp[col];
#pragma unroll
    for (int rb = 0; rb < RB; ++rb)
#pragma unroll
      for (int i = 0; i < 4; ++i) {
        int row = rowbase + rb*16 + q*4 + i;
        float v = swishf(acc[rb][nt][i] + bias);
        int byte = row*outPitchB + col*2; byte ^= ((row & 7) << 4);
        *(uint16_t*)((char*)outb + byte) = f2bf(v);
      }
  }
}

// ---------------- edge megakernel (64 edges / block, 8 waves, 2 blocks/CU, 128 VGPR cap) ----------------
template<int LAYER>
__global__ __launch_bounds__(512, 2)
void edge_kernel(const float* __restrict__ pos, const int* __restrict__ eidx,
                 const char* __restrict__ ws, float* __restrict__ aggout,
                 const float* __restrict__ hsrc)
{
  __shared__ __align__(16) uint16_t bigb[MT*512];  // act1 -> act2 -> (overlay: f32 scratch)
  __shared__ __align__(16) uint16_t smlb[MT*64];   // basis -> x3
  __shared__ float shl[MT*3];
  __shared__ float rbuf[MT];
  __shared__ int   rowl[MT];
  __shared__ int   coll[MT];

  const uint16_t* W1p = (const uint16_t*)(ws + (LAYER==1 ? OFF_W1P1 : OFF_W1P2));
  const uint16_t* W2p = (const uint16_t*)(ws + (LAYER==1 ? OFF_W2P1 : OFF_W2P2));
  const uint16_t* W3p = (const uint16_t*)(ws + (LAYER==1 ? OFF_W3P1 : OFF_W3P2));
  const uint16_t* W4p = (const uint16_t*)(ws + (LAYER==1 ? OFF_W4P1 : OFF_W4P2));
  const float* b1p = (const float*)(ws + (LAYER==1 ? OFF_B1P1 : OFF_B1P2));
  const float* b2p = (const float*)(ws + (LAYER==1 ? OFF_B2P1 : OFF_B2P2));
  const float* b3p = (const float*)(ws + (LAYER==1 ? OFF_B3P1 : OFF_B3P2));
  const float* b4p = (const float*)(ws + (LAYER==1 ? OFF_B4P1 : OFF_B4P2));

  const int tid  = threadIdx.x;
  const int lane = tid & 63;
  const int wv   = tid >> 6;
  const int e0   = blockIdx.x * MT;

  // stage 0: edge meta
  if (tid < MT) {
    int e = e0 + tid;
    int rn = eidx[e];
    int cn = eidx[E_EDGES + e];
    rowl[tid] = rn; coll[tid] = cn;
    float ax = pos[rn*3+0] - pos[cn*3+0];
    float ay = pos[rn*3+1] - pos[cn*3+1];
    float az = pos[rn*3+2] - pos[cn*3+2];
    float rr = sqrtf(ax*ax + ay*ay + az*az + 1e-12f);
    rbuf[tid] = rr;
    float s = SQRT3C * SH0C / rr;
    shl[tid*3+0] = ax*s; shl[tid*3+1] = ay*s; shl[tid*3+2] = az*s;
  }
  __syncthreads();

  // stage 0b: basis into smlb (pitch 64 elems, swizzled bf16)
  for (int i = tid; i < MT*64; i += 512) {
    int e = i >> 6, c = i & 63;
    float v = 0.f;
    if (c < 40) { float t = rbuf[e]*3.9f - (float)c; v = __expf(-t*t); }
    int byte = (e*64 + c)*2; byte ^= ((e & 7) << 4);
    *(uint16_t*)((char*)smlb + byte) = f2bf(v);
  }
  __syncthreads();

  // GEMM1: basis(smlb,64) -> act1(bigb,512), swish. wave: 4 rowblocks x 4 ntiles
  {
    f32x4 acc[4][4];
    gemm_core<64, 4, 4>(smlb, W1p, 32, wv*4, 0, lane, acc);
    gemm_epi<4, 4>(bigb, b1p, wv*4, 0, lane, 1024, acc);
  }
  __syncthreads();

  // GEMM2: act1(bigb) -> act2(bigb), swish. acc in regs across barrier (in-place swap)
  {
    f32x4 acc[4][4];
    gemm_core<512, 4, 4>(bigb, W2p, 32, wv*4, 0, lane, acc);
    __syncthreads();   // all waves done READING act1
    gemm_epi<4, 4>(bigb, b2p, wv*4, 0, lane, 1024, acc);
  }
  __syncthreads();

  // GEMM3: act2(bigb) -> x3(smlb,64), swish. wave: rows (wv>>2)*32, ntile wv&3
  {
    f32x4 acc[2][1];
    gemm_core<512, 2, 1>(bigb, W3p, 4, wv & 3, (wv >> 2)*32, lane, acc);
    gemm_epi<2, 1>(smlb, b3p, wv & 3, (wv >> 2)*32, lane, 128, acc);
  }
  __syncthreads();

  // stage 6: overlay scratch in bigb (act2 dead), gather xj
  float* const bigf = (float*)bigb;
  if (LAYER == 1) {
    float* mbuf = bigf;               // [MT*50]
    float* xjb  = bigf + MT*50;       // [MT*30]
    for (int i = tid; i < MT*50; i += 512) mbuf[i] = 0.f;
    for (int i = tid; i < MT*30; i += 512) {
      int e = i/30, u = i - e*30;
      xjb[i] = hsrc[(size_t)rowl[e]*32 + u];
    }
  } else {
    float* medge = bigf;              // [MT]
    float* Db    = bigf + MT;         // [MT*10]
    float* xjs   = Db + MT*10;        // [MT*30]
    float* xjv   = xjs + MT*30;       // [MT*30]
    if (tid < MT) medge[tid] = 0.f;
    for (int i = tid; i < MT*60; i += 512) {
      int e = i/60, u = i - e*60;
      float v = hsrc[(size_t)rowl[e]*64 + u];
      if (u < 30) xjs[e*30 + u] = v; else xjv[e*30 + (u - 30)] = v;
    }
    __syncthreads();
    for (int i = tid; i < MT*10; i += 512) {
      int e = i/10, v = i - e*10;
      float d = 0.f;
#pragma unroll
      for (int m = 0; m < 3; ++m) d += xjv[e*30 + v*3 + m] * shl[e*3 + m];
      Db[i] = d * INV_SQRT3;
    }
  }
  __syncthreads();

  // GEMM4 + consumption
  const int r_ = lane & 15, q_ = lane >> 4;
  f32x4 zv = {0.f, 0.f, 0.f, 0.f};
  if (LAYER == 1) {
    float* mbuf = bigf;
    float* xjb  = bigf + MT*50;
    const bf16x8* __restrict__ bv4 = reinterpret_cast<const bf16x8*>(W4p);
#pragma unroll
    for (int rh = 0; rh < 2; ++rh) {          // row halves: rowblocks rh*2 + rbi
      bf16x8 a4[2][2];
#pragma unroll
      for (int kk = 0; kk < 2; ++kk)
#pragma unroll
        for (int rbi = 0; rbi < 2; ++rbi) {
          int row = (rh*2 + rbi)*16 + r_;
          int byte = (row*64 + kk*32 + q_*8)*2; byte ^= ((row & 7) << 4);
          a4[kk][rbi] = *reinterpret_cast<const bf16x8*>((const char*)smlb + byte);
        }
#pragma unroll
      for (int ch = 0; ch < 3; ++ch) {
        bf16x8 b4[2][4];
#pragma unroll
        for (int kk = 0; kk < 2; ++kk)
#pragma unroll
          for (int nt = 0; nt < 4; ++nt)
            b4[kk][nt] = bv4[(size_t)(kk*96 + wv*12 + ch*4 + nt)*64 + lane];
        f32x4 acc[2][4];
#pragma unroll
        for (int a = 0; a < 2; ++a)
#pragma unroll
          for (int b = 0; b < 4; ++b) acc[a][b] = zv;
#pragma unroll
        for (int kk = 0; kk < 2; ++kk)
#pragma unroll
          for (int nt = 0; nt < 4; ++nt)
#pragma unroll
            for (int rbi = 0; rbi < 2; ++rbi)
              acc[rbi][nt] = __builtin_amdgcn_mfma_f32_16x16x32_bf16(a4[kk][rbi], b4[kk][nt], acc[rbi][nt], 0, 0, 0);
#pragma unroll
        for (int nt = 0; nt < 4; ++nt) {
          int cg = (wv*12 + ch*4 + nt)*16 + r_;
          if (cg < 1500) {
            float bias = b4p[cg];
            int u, vd;
            if (cg < 1200) { u = cg/40; vd = cg - u*40; }
            else { int cc = cg - 1200; u = cc/10; vd = 40 + (cc - u*10); }
#pragma unroll
            for (int rbi = 0; rbi < 2; ++rbi)
#pragma unroll
              for (int i2 = 0; i2 < 4; ++i2) {
                int e = (rh*2 + rbi)*16 + q_*4 + i2;
                float w = acc[rbi][nt][i2] + bias;
                atomicAdd(&mbuf[e*50 + vd], xjb[e*30 + u] * w);
              }
          }
        }
      }
    }
  } else {
    float* medge = bigf;
    float* Db    = bigf + MT;
    float* xjs   = Db + MT*10;
    const bf16x8* __restrict__ bv4 = reinterpret_cast<const bf16x8*>(W4p);
    // wave wv: rowblocks (wv>>2)*2 + {0,1}, ntile wv&3
    const int rbase = (wv >> 2)*2, nt4 = wv & 3;
    bf16x8 a4[2][2];
#pragma unroll
    for (int kk = 0; kk < 2; ++kk)
#pragma unroll
      for (int rbi = 0; rbi < 2; ++rbi) {
        int row = (rbase + rbi)*16 + r_;
        int byte = (row*64 + kk*32 + q_*8)*2; byte ^= ((row & 7) << 4);
        a4[kk][rbi] = *reinterpret_cast<const bf16x8*>((const char*)smlb + byte);
      }
    f32x4 acc[2];
    acc[0] = zv; acc[1] = zv;
#pragma unroll
    for (int kk = 0; kk < 2; ++kk) {
      bf16x8 b4 = bv4[(size_t)(kk*4 + nt4)*64 + lane];
#pragma unroll
      for (int rbi = 0; rbi < 2; ++rbi)
        acc[rbi] = __builtin_amdgcn_mfma_f32_16x16x32_bf16(a4[kk][rbi], b4, acc[rbi], 0, 0, 0);
    }
    int cg = nt4*16 + r_;
    if (cg < 40) {
      float bias = b4p[cg];
#pragma unroll
      for (int rbi = 0; rbi < 2; ++rbi)
#pragma unroll
        for (int i2 = 0; i2 < 4; ++i2) {
          int e = (rbase + rbi)*16 + q_*4 + i2;
          float w = acc[rbi][i2] + bias;
          float contrib = (cg < 30) ? xjs[e*30 + cg] * w * (SH0C * INV_SQRT30)
                                    : Db[e*10 + (cg - 30)] * w * INV_SQRT10;
          atomicAdd(&medge[e], contrib);
        }
    }
  }
  __syncthreads();

  // scatter to aggregation buffers
  if (LAYER == 1) {
    float* mbuf = bigf;
    for (int i = tid; i < MT*70; i += 512) {
      int e = i/70, c = i - e*70;
      float v;
      if (c < 40) v = mbuf[e*50 + c] * SH0C;
      else { int vv = (c - 40)/3, k = (c - 40) - vv*3; v = mbuf[e*50 + 40 + vv] * shl[e*3 + k]; }
      atomicAdd(&aggout[(size_t)coll[e]*70 + c], v);
    }
  } else {
    float* medge = bigf;
    if (tid < MT) atomicAdd(&aggout[coll[tid]], medge[tid]);
  }
}

// ---------------- node kernels ----------------
__global__ void node_mid(char* ws, const float* __restrict__ si1w)
{
  int nid = blockIdx.x * blockDim.x + threadIdx.x;
  if (nid >= N_NODES) return;
  const float* hN  = (const float*)(ws + OFF_HN)  + (size_t)nid*32;
  const float* agg = (const float*)(ws + OFF_AGG) + (size_t)nid*70;
  float* h2        = (float*)(ws + OFF_H2)        + (size_t)nid*64;

  float hn[30];
#pragma unroll
  for (int u = 0; u < 30; ++u) hn[u] = hN[u];

  float h1[70];
#pragma unroll
  for (int v = 0; v < 40; ++v) {
    float s = 0.f;
#pragma unroll
    for (int u = 0; u < 30; ++u) s += hn[u] * si1w[u*40 + v];
    h1[v] = SQ2C * (s + agg[v]);
  }
#pragma unroll
  for (int c = 40; c < 70; ++c) h1[c] = agg[c];

#pragma unroll
  for (int u = 0; u < 30; ++u) h2[u] = swishf(h1[u]);
#pragma unroll
  for (int v = 0; v < 10; ++v) {
    float g = 1.f / (1.f + __expf(-h1[30 + v]));
#pragma unroll
    for (int k = 0; k < 3; ++k) h2[30 + v*3 + k] = h1[40 + v*3 + k] * g;
  }
}

__global__ void node_final(char* ws, const float* __restrict__ si2w, const int* __restrict__ batch)
{
  __shared__ float ls[NGRAPH];
  if (threadIdx.x < NGRAPH) ls[threadIdx.x] = 0.f;
  __syncthreads();
  int nid = blockIdx.x * blockDim.x + threadIdx.x;
  if (nid < N_NODES) {
    const float* h2   = (const float*)(ws + OFF_H2) + (size_t)nid*64;
    const float* agg2 = (const float*)(ws + OFF_AGG2);
    float s2 = 0.f;
#pragma unroll
    for (int u = 0; u < 30; ++u) s2 += h2[u] * si2w[u];
    float val = SQ2C * (s2 * INV_SQRT30 + agg2[nid]);
    atomicAdd(&ls[batch[nid]], val);
  }
  __syncthreads();
  if (threadIdx.x < NGRAPH)
    atomicAdd(((float*)(ws + OFF_GSUM)) + threadIdx.x, ls[threadIdx.x]);
}

__global__ void write_out(const char* ws, float* out)
{
  int g = threadIdx.x;
  if (g < NGRAPH) out[g] = ((const float*)(ws + OFF_GSUM))[g];
}

// ---------------- launch ----------------
extern "C" void kernel_launch(void* const* d_in, const int* in_sizes, int n_in,
                              void* d_out, int out_size, void* d_ws, size_t ws_size,
                              hipStream_t stream)
{
  const float* pos  = (const float*)d_in[0];
  const float* emb  = (const float*)d_in[1];
  const float* si1w = (const float*)d_in[2];
  const float* si2w = (const float*)d_in[3];
  const float* w1a = (const float*)d_in[4];  const float* b1a = (const float*)d_in[5];
  const float* w2a = (const float*)d_in[6];  const float* b2a = (const float*)d_in[7];
  const float* w3a = (const float*)d_in[8];  const float* b3a = (const float*)d_in[9];
  const float* w4a = (const float*)d_in[10]; const float* b4a = (const float*)d_in[11];
  const float* w1b = (const float*)d_in[12]; const float* b1b = (const float*)d_in[13];
  const float* w2b = (const float*)d_in[14]; const float* b2b = (const float*)d_in[15];
  const float* w3b = (const float*)d_in[16]; const float* b3b = (const float*)d_in[17];
  const float* w4b = (const float*)d_in[18]; const float* b4b = (const float*)d_in[19];
  const int* z     = (const int*)d_in[20];
  const int* eidx  = (const int*)d_in[21];
  const int* batch = (const int*)d_in[22];
  char* ws = (char*)d_ws;

  hipMemsetAsync(ws + OFF_AGG, 0, OFF_END - OFF_AGG, stream);

  prep_kernel<<<1409, 256, 0, stream>>>(w1a, w2a, w3a, w4a, w1b, w2b, w3b, w4b,
                                        b1a, b2a, b3a, b4a, b1b, b2b, b3b, b4b,
                                        emb, z, ws);

  edge_kernel<1><<<E_EDGES/MT, 512, 0, stream>>>(pos, eidx, ws,
                                                 (float*)(ws + OFF_AGG),
                                                 (const float*)(ws + OFF_HN));

  node_mid<<<N_NODES/256, 256, 0, stream>>>(ws, si1w);

  edge_kernel<2><<<E_EDGES/MT, 512, 0, stream>>>(pos, eidx, ws,
                                                 (float*)(ws + OFF_AGG2),
                                                 (const float*)(ws + OFF_H2));

  node_final<<<N_NODES/256, 256, 0, stream>>>(ws, si2w, batch);

  write_out<<<1, 64, 0, stream>>>(ws, (float*)d_out);
}

// Round 8
// 1810.445 us; speedup vs baseline: 1.2191x; 1.0443x over previous
//
#include <hip/hip_runtime.h>
#include <stdint.h>

typedef __attribute__((ext_vector_type(8))) short bf16x8;
typedef __attribute__((ext_vector_type(4))) float f32x4;

#define N_NODES 8192
#define E_EDGES 163840
#define NGRAPH  32
#define MT      64          /* edges per block */

#define INV_SQRT30 0.18257419f
#define SH0C       0.22360680f   /* 1/sqrt(20) */
#define SQRT3C     1.73205081f
#define INV_SQRT3  0.57735027f
#define INV_SQRT10 0.31622777f
#define SQ2C       0.70710678f

// ---------------- workspace layout (bytes) ----------------
enum : unsigned {
  OFF_W1P1 = 0u,       OFF_W2P1 = 65536u,   OFF_W3P1 = 589824u,  OFF_W4P1 = 655360u,
  OFF_W1P2 = 851968u,  OFF_W2P2 = 917504u,  OFF_W3P2 = 1441792u, OFF_W4P2 = 1507328u,
  OFF_B1P1 = 1515520u, OFF_B2P1 = 1517568u, OFF_B3P1 = 1519616u, OFF_B4P1 = 1519872u,
  OFF_B1P2 = 1526016u, OFF_B2P2 = 1528064u, OFF_B3P2 = 1530112u, OFF_B4P2 = 1530368u,
  OFF_HN   = 1530624u, // [8192][32] f32  (emb[z]/sqrt(30))
  OFF_H2   = 2579200u, // [8192][64] f32
  OFF_AGG  = 4676352u, // [8192][70] f32
  OFF_AGG2 = 6970112u, // [8192] f32
  OFF_GSUM = 7002880u, // [32] f32
  OFF_END  = 7003008u
};

__device__ __forceinline__ uint16_t f2bf(float f){
  union { float f; uint32_t u; } v; v.f = f;
  uint32_t r = v.u + 0x7fffu + ((v.u >> 16) & 1u);
  return (uint16_t)(r >> 16);
}
__device__ __forceinline__ float swishf(float x){ return x / (1.f + __expf(-x)); }

// ---------------- weight pre-pack (f32 src -> bf16 MFMA B-fragment order) ----------------
__device__ __forceinline__ void pack_mat(const float* __restrict__ src, int K, int N, int NP,
                                         uint16_t* __restrict__ dst, int t)
{
  int lane = t & 63;
  int tile = t >> 6;
  int NT = NP >> 4;
  int nn = tile % NT, kk = tile / NT;
  int k0 = kk*32 + ((lane >> 4) << 3);
  int n  = nn*16 + (lane & 15);
  union { short s[8]; bf16x8 v; } tmp;
#pragma unroll
  for (int b = 0; b < 8; ++b) {
    int k = k0 + b;
    tmp.s[b] = (k < K && n < N) ? (short)f2bf(src[(size_t)k*N + n]) : (short)0;
  }
  *reinterpret_cast<bf16x8*>(dst + (size_t)t*8) = tmp.v;
}

__global__ void prep_kernel(const float* w1a, const float* w2a, const float* w3a, const float* w4a,
                            const float* w1b, const float* w2b, const float* w3b, const float* w4b,
                            const float* b1a, const float* b2a, const float* b3a, const float* b4a,
                            const float* b1b, const float* b2b, const float* b3b, const float* b4b,
                            const float* emb, const int* z, char* ws)
{
  int t = blockIdx.x * 256 + threadIdx.x;
  if      (t < 4096)   pack_mat(w1a, 40, 500, 512,  (uint16_t*)(ws + OFF_W1P1), t);
  else if (t < 36864)  pack_mat(w2a, 500,500, 512,  (uint16_t*)(ws + OFF_W2P1), t - 4096);
  else if (t < 40960)  pack_mat(w3a, 500, 50, 64,   (uint16_t*)(ws + OFF_W3P1), t - 36864);
  else if (t < 53248)  pack_mat(w4a, 50,1500, 1536, (uint16_t*)(ws + OFF_W4P1), t - 40960);
  else if (t < 57344)  pack_mat(w1b, 40, 500, 512,  (uint16_t*)(ws + OFF_W1P2), t - 53248);
  else if (t < 90112)  pack_mat(w2b, 500,500, 512,  (uint16_t*)(ws + OFF_W2P2), t - 57344);
  else if (t < 94208)  pack_mat(w3b, 500, 50, 64,   (uint16_t*)(ws + OFF_W3P2), t - 90112);
  else if (t < 94720)  pack_mat(w4b, 50,  40, 64,   (uint16_t*)(ws + OFF_W4P2), t - 94208);
  else if (t < 98496) {
    int loc = t - 94720;
    const float* src; float* dst; int realN;
    if      (loc < 512)  { src=b1a; dst=(float*)(ws+OFF_B1P1); realN=500; }
    else if (loc < 1024) { src=b2a; dst=(float*)(ws+OFF_B2P1); realN=500;  loc -= 512;  }
    else if (loc < 1088) { src=b3a; dst=(float*)(ws+OFF_B3P1); realN=50;   loc -= 1024; }
    else if (loc < 2624) { src=b4a; dst=(float*)(ws+OFF_B4P1); realN=1500; loc -= 1088; }
    else if (loc < 3136) { src=b1b; dst=(float*)(ws+OFF_B1P2); realN=500;  loc -= 2624; }
    else if (loc < 3648) { src=b2b; dst=(float*)(ws+OFF_B2P2); realN=500;  loc -= 3136; }
    else if (loc < 3712) { src=b3b; dst=(float*)(ws+OFF_B3P2); realN=50;   loc -= 3648; }
    else                 { src=b4b; dst=(float*)(ws+OFF_B4P2); realN=40;   loc -= 3712; }
    dst[loc] = (loc < realN) ? src[loc] : 0.f;
  }
  else if (t < 360640) {
    int i = t - 98496;
    int n = i >> 5, u = i & 31;
    float v = 0.f;
    if (u < 30) v = emb[(size_t)z[n]*30 + u] * INV_SQRT30;
    ((float*)(ws + OFF_HN))[i] = v;
  }
}

// ---------------- GEMM core: TIGHT k-loop (no unroll => small I-footprint) ----------------
template<int KP, int RB, int NTW>
__device__ __forceinline__ void gemm_core(const uint16_t* inb, const uint16_t* __restrict__ Bp,
                                          int NTtot, int ntbase, int rowbase, int lane,
                                          f32x4 (&acc)[RB][NTW])
{
  const int r = lane & 15, q = lane >> 4;
  constexpr int NK = KP/32;
  const bf16x8* __restrict__ bv = reinterpret_cast<const bf16x8*>(Bp);
  const char* inbc = (const char*)inb;
  f32x4 zv = {0.f, 0.f, 0.f, 0.f};
#pragma unroll
  for (int a = 0; a < RB; ++a)
#pragma unroll
    for (int b = 0; b < NTW; ++b) acc[a][b] = zv;

#pragma unroll 1
  for (int kk = 0; kk < NK; ++kk) {
    bf16x8 afrag[RB];
#pragma unroll
    for (int rb = 0; rb < RB; ++rb) {
      int row = rowbase + rb*16 + r;
      int byte = (row*KP + kk*32 + q*8) * 2; byte ^= ((row & 7) << 4);
      afrag[rb] = *reinterpret_cast<const bf16x8*>(inbc + byte);
    }
    bf16x8 bfrag[NTW];
#pragma unroll
    for (int nt = 0; nt < NTW; ++nt)
      bfrag[nt] = bv[(size_t)(kk*NTtot + ntbase + nt)*64 + lane];
#pragma unroll
    for (int nt = 0; nt < NTW; ++nt)
#pragma unroll
      for (int rb = 0; rb < RB; ++rb)
        acc[rb][nt] = __builtin_amdgcn_mfma_f32_16x16x32_bf16(afrag[rb], bfrag[nt], acc[rb][nt], 0, 0, 0);
  }
}

template<int RB, int NTW>
__device__ __forceinline__ void gemm_epi(uint16_t* outb, const float* __restrict__ bp,
                                         int ntbase, int rowbase, int lane, int outPitchB,
                                         f32x4 (&acc)[RB][NTW])
{
  const int r = lane & 15, q = lane >> 4;
#pragma unroll
  for (int nt = 0; nt < NTW; ++nt) {
    int col = (ntbase + nt)*16 + r;
    float bias = bp[col];
#pragma unroll
    for (int rb = 0; rb < RB; ++rb)
#pragma unroll
      for (int i = 0; i < 4; ++i) {
        int row = rowbase + rb*16 + q*4 + i;
        float v = swishf(acc[rb][nt][i] + bias);
        int byte = row*outPitchB + col*2; byte ^= ((row & 7) << 4);
        *(uint16_t*)((char*)outb + byte) = f2bf(v);
      }
  }
}

// ---------------- edge megakernel (64 edges / block, 8 waves) ----------------
template<int LAYER>
__global__ __launch_bounds__(512, 2)
void edge_kernel(const float* __restrict__ pos, const int* __restrict__ eidx,
                 const char* __restrict__ ws, float* __restrict__ aggout,
                 const float* __restrict__ hsrc)
{
  __shared__ __align__(16) uint16_t bigb[MT*512];  // act1 -> act2 -> (overlay: f32 scratch)
  __shared__ __align__(16) uint16_t smlb[MT*64];   // basis -> x3
  __shared__ float shl[MT*3];
  __shared__ float rbuf[MT];
  __shared__ int   rowl[MT];
  __shared__ int   coll[MT];

  const uint16_t* W1p = (const uint16_t*)(ws + (LAYER==1 ? OFF_W1P1 : OFF_W1P2));
  const uint16_t* W2p = (const uint16_t*)(ws + (LAYER==1 ? OFF_W2P1 : OFF_W2P2));
  const uint16_t* W3p = (const uint16_t*)(ws + (LAYER==1 ? OFF_W3P1 : OFF_W3P2));
  const uint16_t* W4p = (const uint16_t*)(ws + (LAYER==1 ? OFF_W4P1 : OFF_W4P2));
  const float* b1p = (const float*)(ws + (LAYER==1 ? OFF_B1P1 : OFF_B1P2));
  const float* b2p = (const float*)(ws + (LAYER==1 ? OFF_B2P1 : OFF_B2P2));
  const float* b3p = (const float*)(ws + (LAYER==1 ? OFF_B3P1 : OFF_B3P2));
  const float* b4p = (const float*)(ws + (LAYER==1 ? OFF_B4P1 : OFF_B4P2));

  const int tid  = threadIdx.x;
  const int lane = tid & 63;
  const int wv   = tid >> 6;
  const int e0   = blockIdx.x * MT;

  // stage 0: edge meta
  if (tid < MT) {
    int e = e0 + tid;
    int rn = eidx[e];
    int cn = eidx[E_EDGES + e];
    rowl[tid] = rn; coll[tid] = cn;
    float ax = pos[rn*3+0] - pos[cn*3+0];
    float ay = pos[rn*3+1] - pos[cn*3+1];
    float az = pos[rn*3+2] - pos[cn*3+2];
    float rr = sqrtf(ax*ax + ay*ay + az*az + 1e-12f);
    rbuf[tid] = rr;
    float s = SQRT3C * SH0C / rr;
    shl[tid*3+0] = ax*s; shl[tid*3+1] = ay*s; shl[tid*3+2] = az*s;
  }
  __syncthreads();

  // stage 0b: basis into smlb (pitch 64 elems, swizzled bf16)
#pragma unroll 1
  for (int i = tid; i < MT*64; i += 512) {
    int e = i >> 6, c = i & 63;
    float v = 0.f;
    if (c < 40) { float t = rbuf[e]*3.9f - (float)c; v = __expf(-t*t); }
    int byte = (e*64 + c)*2; byte ^= ((e & 7) << 4);
    *(uint16_t*)((char*)smlb + byte) = f2bf(v);
  }
  __syncthreads();

  // GEMM1: basis(smlb,64) -> act1(bigb,512), swish. wave: 4 rowblocks x 4 ntiles
  {
    f32x4 acc[4][4];
    gemm_core<64, 4, 4>(smlb, W1p, 32, wv*4, 0, lane, acc);
    gemm_epi<4, 4>(bigb, b1p, wv*4, 0, lane, 1024, acc);
  }
  __syncthreads();

  // GEMM2: act1(bigb) -> act2(bigb), swish. acc in regs across barrier (in-place swap)
  {
    f32x4 acc[4][4];
    gemm_core<512, 4, 4>(bigb, W2p, 32, wv*4, 0, lane, acc);
    __syncthreads();   // all waves done READING act1
    gemm_epi<4, 4>(bigb, b2p, wv*4, 0, lane, 1024, acc);
  }
  __syncthreads();

  // GEMM3: act2(bigb) -> x3(smlb,64), swish. wave: rows (wv>>2)*32, ntile wv&3
  {
    f32x4 acc[2][1];
    gemm_core<512, 2, 1>(bigb, W3p, 4, wv & 3, (wv >> 2)*32, lane, acc);
    gemm_epi<2, 1>(smlb, b3p, wv & 3, (wv >> 2)*32, lane, 128, acc);
  }
  __syncthreads();

  // stage 6: overlay scratch in bigb (act2 dead), gather xj
  float* const bigf = (float*)bigb;
  if (LAYER == 1) {
    float* mbuf = bigf;               // [MT*50]
    float* xjb  = bigf + MT*50;       // [MT*30]
#pragma unroll 1
    for (int i = tid; i < MT*50; i += 512) mbuf[i] = 0.f;
#pragma unroll 1
    for (int i = tid; i < MT*30; i += 512) {
      int e = i/30, u = i - e*30;
      xjb[i] = hsrc[(size_t)rowl[e]*32 + u];
    }
  } else {
    float* medge = bigf;              // [MT]
    float* Db    = bigf + MT;         // [MT*10]
    float* xjs   = Db + MT*10;        // [MT*30]
    float* xjv   = xjs + MT*30;       // [MT*30]
    if (tid < MT) medge[tid] = 0.f;
#pragma unroll 1
    for (int i = tid; i < MT*60; i += 512) {
      int e = i/60, u = i - e*60;
      float v = hsrc[(size_t)rowl[e]*64 + u];
      if (u < 30) xjs[e*30 + u] = v; else xjv[e*30 + (u - 30)] = v;
    }
    __syncthreads();
#pragma unroll 1
    for (int i = tid; i < MT*10; i += 512) {
      int e = i/10, v = i - e*10;
      float d = 0.f;
#pragma unroll
      for (int m = 0; m < 3; ++m) d += xjv[e*30 + v*3 + m] * shl[e*3 + m];
      Db[i] = d * INV_SQRT3;
    }
  }
  __syncthreads();

  // GEMM4 + consumption
  const int r_ = lane & 15, q_ = lane >> 4;
  f32x4 zv = {0.f, 0.f, 0.f, 0.f};
  if (LAYER == 1) {
    float* mbuf = bigf;
    float* xjb  = bigf + MT*50;
    const bf16x8* __restrict__ bv4 = reinterpret_cast<const bf16x8*>(W4p);
#pragma unroll 1
    for (int rh = 0; rh < 2; ++rh) {          // row halves: rowblocks rh*2 + rbi
      bf16x8 a4[2][2];
#pragma unroll
      for (int kk = 0; kk < 2; ++kk)
#pragma unroll
        for (int rbi = 0; rbi < 2; ++rbi) {
          int row = (rh*2 + rbi)*16 + r_;
          int byte = (row*64 + kk*32 + q_*8)*2; byte ^= ((row & 7) << 4);
          a4[kk][rbi] = *reinterpret_cast<const bf16x8*>((const char*)smlb + byte);
        }
#pragma unroll 1
      for (int ch = 0; ch < 3; ++ch) {
        bf16x8 b4[2][4];
#pragma unroll
        for (int kk = 0; kk < 2; ++kk)
#pragma unroll
          for (int nt = 0; nt < 4; ++nt)
            b4[kk][nt] = bv4[(size_t)(kk*96 + wv*12 + ch*4 + nt)*64 + lane];
        f32x4 acc[2][4];
#pragma unroll
        for (int a = 0; a < 2; ++a)
#pragma unroll
          for (int b = 0; b < 4; ++b) acc[a][b] = zv;
#pragma unroll
        for (int kk = 0; kk < 2; ++kk)
#pragma unroll
          for (int nt = 0; nt < 4; ++nt)
#pragma unroll
            for (int rbi = 0; rbi < 2; ++rbi)
              acc[rbi][nt] = __builtin_amdgcn_mfma_f32_16x16x32_bf16(a4[kk][rbi], b4[kk][nt], acc[rbi][nt], 0, 0, 0);
#pragma unroll
        for (int nt = 0; nt < 4; ++nt) {
          int cg = (wv*12 + ch*4 + nt)*16 + r_;
          if (cg < 1500) {
            float bias = b4p[cg];
            int u, vd;
            if (cg < 1200) { u = cg/40; vd = cg - u*40; }
            else { int cc = cg - 1200; u = cc/10; vd = 40 + (cc - u*10); }
#pragma unroll
            for (int rbi = 0; rbi < 2; ++rbi)
#pragma unroll
              for (int i2 = 0; i2 < 4; ++i2) {
                int e = (rh*2 + rbi)*16 + q_*4 + i2;
                float w = acc[rbi][nt][i2] + bias;
                atomicAdd(&mbuf[e*50 + vd], xjb[e*30 + u] * w);
              }
          }
        }
      }
    }
  } else {
    float* medge = bigf;
    float* Db    = bigf + MT;
    float* xjs   = Db + MT*10;
    const bf16x8* __restrict__ bv4 = reinterpret_cast<const bf16x8*>(W4p);
    // wave wv: rowblocks (wv>>2)*2 + {0,1}, ntile wv&3
    const int rbase = (wv >> 2)*2, nt4 = wv & 3;
    bf16x8 a4[2][2];
#pragma unroll
    for (int kk = 0; kk < 2; ++kk)
#pragma unroll
      for (int rbi = 0; rbi < 2; ++rbi) {
        int row = (rbase + rbi)*16 + r_;
        int byte = (row*64 + kk*32 + q_*8)*2; byte ^= ((row & 7) << 4);
        a4[kk][rbi] = *reinterpret_cast<const bf16x8*>((const char*)smlb + byte);
      }
    f32x4 acc[2];
    acc[0] = zv; acc[1] = zv;
#pragma unroll
    for (int kk = 0; kk < 2; ++kk) {
      bf16x8 b4 = bv4[(size_t)(kk*4 + nt4)*64 + lane];
#pragma unroll
      for (int rbi = 0; rbi < 2; ++rbi)
        acc[rbi] = __builtin_amdgcn_mfma_f32_16x16x32_bf16(a4[kk][rbi], b4, acc[rbi], 0, 0, 0);
    }
    int cg = nt4*16 + r_;
    if (cg < 40) {
      float bias = b4p[cg];
#pragma unroll
      for (int rbi = 0; rbi < 2; ++rbi)
#pragma unroll
        for (int i2 = 0; i2 < 4; ++i2) {
          int e = (rbase + rbi)*16 + q_*4 + i2;
          float w = acc[rbi][i2] + bias;
          float contrib = (cg < 30) ? xjs[e*30 + cg] * w * (SH0C * INV_SQRT30)
                                    : Db[e*10 + (cg - 30)] * w * INV_SQRT10;
          atomicAdd(&medge[e], contrib);
        }
    }
  }
  __syncthreads();

  // scatter to aggregation buffers
  if (LAYER == 1) {
    float* mbuf = bigf;
#pragma unroll 1
    for (int i = tid; i < MT*70; i += 512) {
      int e = i/70, c = i - e*70;
      float v;
      if (c < 40) v = mbuf[e*50 + c] * SH0C;
      else { int vv = (c - 40)/3, k = (c - 40) - vv*3; v = mbuf[e*50 + 40 + vv] * shl[e*3 + k]; }
      atomicAdd(&aggout[(size_t)coll[e]*70 + c], v);
    }
  } else {
    float* medge = bigf;
    if (tid < MT) atomicAdd(&aggout[coll[tid]], medge[tid]);
  }
}

// ---------------- node kernels ----------------
__global__ void node_mid(char* ws, const float* __restrict__ si1w)
{
  int nid = blockIdx.x * blockDim.x + threadIdx.x;
  if (nid >= N_NODES) return;
  const float* hN  = (const float*)(ws + OFF_HN)  + (size_t)nid*32;
  const float* agg = (const float*)(ws + OFF_AGG) + (size_t)nid*70;
  float* h2        = (float*)(ws + OFF_H2)        + (size_t)nid*64;

  float hn[30];
#pragma unroll
  for (int u = 0; u < 30; ++u) hn[u] = hN[u];

  float h1[70];
#pragma unroll 1
  for (int v = 0; v < 40; ++v) {
    float s = 0.f;
#pragma unroll
    for (int u = 0; u < 30; ++u) s += hn[u] * si1w[u*40 + v];
    h1[v] = SQ2C * (s + agg[v]);
  }
#pragma unroll
  for (int c = 40; c < 70; ++c) h1[c] = agg[c];

#pragma unroll
  for (int u = 0; u < 30; ++u) h2[u] = swishf(h1[u]);
#pragma unroll
  for (int v = 0; v < 10; ++v) {
    float g = 1.f / (1.f + __expf(-h1[30 + v]));
#pragma unroll
    for (int k = 0; k < 3; ++k) h2[30 + v*3 + k] = h1[40 + v*3 + k] * g;
  }
}

__global__ void node_final(char* ws, const float* __restrict__ si2w, const int* __restrict__ batch)
{
  __shared__ float ls[NGRAPH];
  if (threadIdx.x < NGRAPH) ls[threadIdx.x] = 0.f;
  __syncthreads();
  int nid = blockIdx.x * blockDim.x + threadIdx.x;
  if (nid < N_NODES) {
    const float* h2   = (const float*)(ws + OFF_H2) + (size_t)nid*64;
    const float* agg2 = (const float*)(ws + OFF_AGG2);
    float s2 = 0.f;
#pragma unroll
    for (int u = 0; u < 30; ++u) s2 += h2[u] * si2w[u];
    float val = SQ2C * (s2 * INV_SQRT30 + agg2[nid]);
    atomicAdd(&ls[batch[nid]], val);
  }
  __syncthreads();
  if (threadIdx.x < NGRAPH)
    atomicAdd(((float*)(ws + OFF_GSUM)) + threadIdx.x, ls[threadIdx.x]);
}

__global__ void write_out(const char* ws, float* out)
{
  int g = threadIdx.x;
  if (g < NGRAPH) out[g] = ((const float*)(ws + OFF_GSUM))[g];
}

// ---------------- launch ----------------
extern "C" void kernel_launch(void* const* d_in, const int* in_sizes, int n_in,
                              void* d_out, int out_size, void* d_ws, size_t ws_size,
                              hipStream_t stream)
{
  const float* pos  = (const float*)d_in[0];
  const float* emb  = (const float*)d_in[1];
  const float* si1w = (const float*)d_in[2];
  const float* si2w = (const float*)d_in[3];
  const float* w1a = (const float*)d_in[4];  const float* b1a = (const float*)d_in[5];
  const float* w2a = (const float*)d_in[6];  const float* b2a = (const float*)d_in[7];
  const float* w3a = (const float*)d_in[8];  const float* b3a = (const float*)d_in[9];
  const float* w4a = (const float*)d_in[10]; const float* b4a = (const float*)d_in[11];
  const float* w1b = (const float*)d_in[12]; const float* b1b = (const float*)d_in[13];
  const float* w2b = (const float*)d_in[14]; const float* b2b = (const float*)d_in[15];
  const float* w3b = (const float*)d_in[16]; const float* b3b = (const float*)d_in[17];
  const float* w4b = (const float*)d_in[18]; const float* b4b = (const float*)d_in[19];
  const int* z     = (const int*)d_in[20];
  const int* eidx  = (const int*)d_in[21];
  const int* batch = (const int*)d_in[22];
  char* ws = (char*)d_ws;

  hipMemsetAsync(ws + OFF_AGG, 0, OFF_END - OFF_AGG, stream);

  prep_kernel<<<1409, 256, 0, stream>>>(w1a, w2a, w3a, w4a, w1b, w2b, w3b, w4b,
                                        b1a, b2a, b3a, b4a, b1b, b2b, b3b, b4b,
                                        emb, z, ws);

  edge_kernel<1><<<E_EDGES/MT, 512, 0, stream>>>(pos, eidx, ws,
                                                 (float*)(ws + OFF_AGG),
                                                 (const float*)(ws + OFF_HN));

  node_mid<<<N_NODES/256, 256, 0, stream>>>(ws, si1w);

  edge_kernel<2><<<E_EDGES/MT, 512, 0, stream>>>(pos, eidx, ws,
                                                 (float*)(ws + OFF_AGG2),
                                                 (const float*)(ws + OFF_H2));

  node_final<<<N_NODES/256, 256, 0, stream>>>(ws, si2w, batch);

  write_out<<<1, 64, 0, stream>>>(ws, (float*)d_out);
}